// Round 2
// baseline (7693.037 us; speedup 1.0000x reference)
//
#include <hip/hip_runtime.h>

// Shapes (fixed by the reference)
#define BB 8
#define SS 1024
#define DD 1024
#define HH 16
#define DK 64
#define FF 4096
#define MM (BB*SS)   // 8192

// ---------------------------------------------------------------------------
// QKV projection: per-head GEMM. N-tile of 64 == exactly one head, so the
// [H,D,DK] weight is 48 independent row-major [1024,64] matrices.
// Output layout: [B,H,S,DK] (attention-friendly).
// grid (M/64, H, 3{q,k,v}), block 256.
// ---------------------------------------------------------------------------
__global__ __launch_bounds__(256) void qkv_gemm(
    const float* __restrict__ src,
    const float* __restrict__ Wq, const float* __restrict__ bq,
    const float* __restrict__ Wk, const float* __restrict__ bk,
    const float* __restrict__ Wv, const float* __restrict__ bv,
    float* __restrict__ qo, float* __restrict__ ko, float* __restrict__ vo) {
  const int m0 = blockIdx.x * 64;
  const int h  = blockIdx.y;
  const int z  = blockIdx.z;
  const float* W    = (z == 0 ? Wq : z == 1 ? Wk : Wv) + (size_t)h * DD * DK;
  const float* bias = (z == 0 ? bq : z == 1 ? bk : bv) + h * DK;
  float* out = (z == 0 ? qo : z == 1 ? ko : vo);

  __shared__ float As[16][64];   // [k][m] transposed
  __shared__ float Bs[16][64];   // [k][n]
  const int tid = threadIdx.x;
  const int tx = tid & 15, ty = tid >> 4;
  float acc[4][4] = {};

  for (int k0 = 0; k0 < DD; k0 += 16) {
    {
      int rowa = tid >> 2, c4 = (tid & 3) * 4;
      float4 av = *(const float4*)(src + (size_t)(m0 + rowa) * DD + k0 + c4);
      As[c4 + 0][rowa] = av.x; As[c4 + 1][rowa] = av.y;
      As[c4 + 2][rowa] = av.z; As[c4 + 3][rowa] = av.w;
    }
    {
      int rowb = tid >> 4, c4 = (tid & 15) * 4;
      *(float4*)(&Bs[rowb][c4]) = *(const float4*)(W + (size_t)(k0 + rowb) * DK + c4);
    }
    __syncthreads();
#pragma unroll
    for (int kk = 0; kk < 16; ++kk) {
      float4 a4 = *(float4*)(&As[kk][ty * 4]);
      float4 b4 = *(float4*)(&Bs[kk][tx * 4]);
      float a[4] = {a4.x, a4.y, a4.z, a4.w};
      float b[4] = {b4.x, b4.y, b4.z, b4.w};
#pragma unroll
      for (int i = 0; i < 4; ++i)
#pragma unroll
        for (int j = 0; j < 4; ++j) acc[i][j] += a[i] * b[j];
    }
    __syncthreads();
  }
  float4 bv4 = *(const float4*)(bias + tx * 4);
  float bb[4] = {bv4.x, bv4.y, bv4.z, bv4.w};
#pragma unroll
  for (int i = 0; i < 4; ++i) {
    int m = m0 + ty * 4 + i;
    int b = m >> 10, s = m & 1023;
    float4 o = {acc[i][0] + bb[0], acc[i][1] + bb[1],
                acc[i][2] + bb[2], acc[i][3] + bb[3]};
    *(float4*)(out + ((size_t)(b * HH + h) * SS + s) * DK + tx * 4) = o;
  }
}

// ---------------------------------------------------------------------------
// Attention: 8 query rows per block; full 8x1024 score strip in LDS (no
// online softmax needed). K/V tiles staged 64x64. Q rows in registers.
// grid (S/8, H, B), block 256. LDS ~51 KB.
// ---------------------------------------------------------------------------
__global__ __launch_bounds__(256) void attention(
    const float* __restrict__ q, const float* __restrict__ k,
    const float* __restrict__ v, const float* __restrict__ mask,
    float* __restrict__ ctx) {
  const int s0 = blockIdx.x * 8;
  const int h = blockIdx.y, b = blockIdx.z;
  const int tid = threadIdx.x;

  __shared__ float P[8 * 1024];      // 32 KB: score strip
  __shared__ float kt[64 * 64];      // 16 KB: K or V tile
  __shared__ float qs[8 * 64];       // 2 KB
  __shared__ float red[8 * 32];      // 1 KB
  __shared__ float rowstat[8];

  const size_t base = ((size_t)(b * HH + h)) * SS * DK;

  if (tid < 128) {
    int r = tid >> 4, d4 = (tid & 15) * 4;
    *(float4*)(qs + r * 64 + d4) = *(const float4*)(q + base + (size_t)(s0 + r) * 64 + d4);
  }
  __syncthreads();

  const int r  = tid >> 5;   // 0..7 (row owned in pass 1)
  const int tl = tid & 31;   // 0..31
  float4 qreg[16];
#pragma unroll
  for (int i = 0; i < 16; ++i) qreg[i] = *(float4*)(qs + r * 64 + i * 4);

  const float* mrow = mask + (size_t)(s0 + r) * SS;

  // ---- pass 1: logits ----
  for (int tile = 0; tile < 16; ++tile) {
#pragma unroll
    for (int i = 0; i < 4; ++i) {
      int lin = tid + i * 256;                  // float4 index, 0..1023
      int tr = lin >> 4, d4 = (lin & 15) * 4;
      *(float4*)(kt + tr * 64 + d4) =
          *(const float4*)(k + base + (size_t)(tile * 64 + tr) * 64 + d4);
    }
    __syncthreads();
#pragma unroll
    for (int j = 0; j < 2; ++j) {
      int tt = tl * 2 + j;
      const float* krow = kt + tt * 64;
      float acc = 0.f;
#pragma unroll
      for (int i = 0; i < 16; ++i) {
        float4 kv = *(float4*)(krow + i * 4);
        acc += qreg[i].x * kv.x + qreg[i].y * kv.y +
               qreg[i].z * kv.z + qreg[i].w * kv.w;
      }
      int tg = tile * 64 + tt;
      P[r * 1024 + tg] = acc * 0.125f + mrow[tg] * (-1e9f);
    }
    __syncthreads();
  }

  // ---- softmax (unnormalized; defer 1/sum to epilogue) ----
  float mx = -1e30f;
  for (int t = tl; t < 1024; t += 32) mx = fmaxf(mx, P[r * 1024 + t]);
  red[r * 32 + tl] = mx;
  __syncthreads();
  mx = -1e30f;
#pragma unroll
  for (int i = 0; i < 32; ++i) mx = fmaxf(mx, red[r * 32 + i]);
  __syncthreads();
  float sm = 0.f;
  for (int t = tl; t < 1024; t += 32) {
    float p = __expf(P[r * 1024 + t] - mx);
    P[r * 1024 + t] = p;
    sm += p;
  }
  red[r * 32 + tl] = sm;
  __syncthreads();
  if (tl == 0) {
    float s = 0.f;
#pragma unroll
    for (int i = 0; i < 32; ++i) s += red[r * 32 + i];
    rowstat[r] = 1.f / s;
  }
  __syncthreads();

  // ---- pass 2: ctx = P @ V ----
  const int kc = tid & 63;   // output column (contiguous across the wave)
  const int rg = tid >> 6;   // wave id: whole wave shares rg -> P reads broadcast
  float acc2[2] = {0.f, 0.f};
  for (int tile = 0; tile < 16; ++tile) {
#pragma unroll
    for (int i = 0; i < 4; ++i) {
      int lin = tid + i * 256;
      int tr = lin >> 4, d4 = (lin & 15) * 4;
      *(float4*)(kt + tr * 64 + d4) =
          *(const float4*)(v + base + (size_t)(tile * 64 + tr) * 64 + d4);
    }
    __syncthreads();
#pragma unroll 16
    for (int tt = 0; tt < 64; ++tt) {
      float vv = kt[tt * 64 + kc];
      int tg = tile * 64 + tt;
      acc2[0] += P[(rg * 2 + 0) * 1024 + tg] * vv;
      acc2[1] += P[(rg * 2 + 1) * 1024 + tg] * vv;
    }
    __syncthreads();
  }
#pragma unroll
  for (int ri = 0; ri < 2; ++ri) {
    int rr = rg * 2 + ri;
    float o = acc2[ri] * rowstat[rr];
    // ctx layout [B, S, H*DK] (head-major concat)
    ctx[((size_t)(b * SS + s0 + rr)) * DD + h * DK + kc] = o;
  }
}

// ---------------------------------------------------------------------------
// Generic fp32 GEMM: C[M,N] = A[M,K] @ B[K,N] (+bias)(+ReLU)(+accumulate).
// B has row stride ldb (allows N-slices of a wider matrix).
// 128x128 tile, BK=16, 8x8 per thread, 256 threads.
// ACC==0: C = acc + bias (ReLU optional). ACC==1: C += acc (no bias/ReLU).
// ---------------------------------------------------------------------------
template <int RELU, int ACC>
__global__ __launch_bounds__(256) void gemm128(
    const float* __restrict__ A, const float* __restrict__ Bm,
    const float* __restrict__ bias, float* __restrict__ C,
    int M, int N, int K, int ldb) {
  const int n0 = blockIdx.x * 128, m0 = blockIdx.y * 128;
  __shared__ float As[16][128];   // [k][m]
  __shared__ float Bs[16][128];   // [k][n]
  const int tid = threadIdx.x;
  const int tx = tid & 15, ty = tid >> 4;
  float acc[8][8] = {};

  const int arow = tid >> 1, ac = (tid & 1) * 8;   // A: 128 rows x 16
  const int brow = tid >> 4, bc = (tid & 15) * 8;  // B: 16 rows x 128

  for (int k0 = 0; k0 < K; k0 += 16) {
    float4 a0 = *(const float4*)(A + (size_t)(m0 + arow) * K + k0 + ac);
    float4 a1 = *(const float4*)(A + (size_t)(m0 + arow) * K + k0 + ac + 4);
    As[ac + 0][arow] = a0.x; As[ac + 1][arow] = a0.y;
    As[ac + 2][arow] = a0.z; As[ac + 3][arow] = a0.w;
    As[ac + 4][arow] = a1.x; As[ac + 5][arow] = a1.y;
    As[ac + 6][arow] = a1.z; As[ac + 7][arow] = a1.w;
    float4 b0 = *(const float4*)(Bm + (size_t)(k0 + brow) * ldb + n0 + bc);
    float4 b1 = *(const float4*)(Bm + (size_t)(k0 + brow) * ldb + n0 + bc + 4);
    *(float4*)(&Bs[brow][bc]) = b0;
    *(float4*)(&Bs[brow][bc + 4]) = b1;
    __syncthreads();
#pragma unroll
    for (int kk = 0; kk < 16; ++kk) {
      float a[8], b[8];
      *(float4*)(a)     = *(float4*)(&As[kk][ty * 8]);
      *(float4*)(a + 4) = *(float4*)(&As[kk][ty * 8 + 4]);
      *(float4*)(b)     = *(float4*)(&Bs[kk][tx * 8]);
      *(float4*)(b + 4) = *(float4*)(&Bs[kk][tx * 8 + 4]);
#pragma unroll
      for (int i = 0; i < 8; ++i)
#pragma unroll
        for (int j = 0; j < 8; ++j) acc[i][j] += a[i] * b[j];
    }
    __syncthreads();
  }

#pragma unroll
  for (int i = 0; i < 8; ++i) {
    int m = m0 + ty * 8 + i;
    float* crow = C + (size_t)m * N + n0 + tx * 8;
#pragma unroll
    for (int j4 = 0; j4 < 2; ++j4) {
      float4 o;
      if (ACC) {
        float4 c = *(float4*)(crow + j4 * 4);
        o.x = c.x + acc[i][j4 * 4 + 0];
        o.y = c.y + acc[i][j4 * 4 + 1];
        o.z = c.z + acc[i][j4 * 4 + 2];
        o.w = c.w + acc[i][j4 * 4 + 3];
      } else {
        const float* bp = bias + n0 + tx * 8 + j4 * 4;
        o.x = acc[i][j4 * 4 + 0] + bp[0];
        o.y = acc[i][j4 * 4 + 1] + bp[1];
        o.z = acc[i][j4 * 4 + 2] + bp[2];
        o.w = acc[i][j4 * 4 + 3] + bp[3];
        if (RELU) {
          o.x = fmaxf(o.x, 0.f); o.y = fmaxf(o.y, 0.f);
          o.z = fmaxf(o.z, 0.f); o.w = fmaxf(o.w, 0.f);
        }
      }
      *(float4*)(crow + j4 * 4) = o;
    }
  }
}

// ---------------------------------------------------------------------------
// Residual + LayerNorm: out = LN(a + r) * w + b. One block per row (D=1024).
// Safe for out == a (each thread reads its own 4 floats before writing them).
// ---------------------------------------------------------------------------
__global__ __launch_bounds__(256) void residual_ln(
    const float* __restrict__ a, const float* __restrict__ rr,
    const float* __restrict__ w, const float* __restrict__ bias,
    float* __restrict__ out) {
  const int row = blockIdx.x;
  const size_t off = (size_t)row * DD + threadIdx.x * 4;
  float4 va = *(const float4*)(a + off);
  float4 vr = *(const float4*)(rr + off);
  float4 x = {va.x + vr.x, va.y + vr.y, va.z + vr.z, va.w + vr.w};
  float s  = x.x + x.y + x.z + x.w;
  float ss = x.x * x.x + x.y * x.y + x.z * x.z + x.w * x.w;
#pragma unroll
  for (int o = 32; o > 0; o >>= 1) {
    s  += __shfl_down(s, o);
    ss += __shfl_down(ss, o);
  }
  __shared__ float2 sred[4];
  int wid = threadIdx.x >> 6;
  if ((threadIdx.x & 63) == 0) sred[wid] = make_float2(s, ss);
  __syncthreads();
  float st = 0.f, sst = 0.f;
#pragma unroll
  for (int i = 0; i < 4; ++i) { st += sred[i].x; sst += sred[i].y; }
  float mu  = st * (1.f / 1024.f);
  float var = sst * (1.f / 1024.f) - mu * mu;
  float rs = rsqrtf(var + 1e-5f);
  float4 vw = *(const float4*)(w + threadIdx.x * 4);
  float4 vb = *(const float4*)(bias + threadIdx.x * 4);
  float4 o;
  o.x = (x.x - mu) * rs * vw.x + vb.x;
  o.y = (x.y - mu) * rs * vw.y + vb.y;
  o.z = (x.z - mu) * rs * vw.z + vb.z;
  o.w = (x.w - mu) * rs * vw.w + vb.w;
  *(float4*)(out + off) = o;
}

// ---------------------------------------------------------------------------
extern "C" void kernel_launch(void* const* d_in, const int* in_sizes, int n_in,
                              void* d_out, int out_size, void* d_ws, size_t ws_size,
                              hipStream_t stream) {
  const float* src  = (const float*)d_in[0];
  const float* mask = (const float*)d_in[1];
  const float* Wq = (const float*)d_in[2];  const float* bq = (const float*)d_in[3];
  const float* Wk = (const float*)d_in[4];  const float* bk = (const float*)d_in[5];
  const float* Wv = (const float*)d_in[6];  const float* bv = (const float*)d_in[7];
  const float* Wo = (const float*)d_in[8];  const float* bo = (const float*)d_in[9];
  const float* ln1w = (const float*)d_in[10]; const float* ln1b = (const float*)d_in[11];
  const float* W1 = (const float*)d_in[12]; const float* b1 = (const float*)d_in[13];
  const float* W2 = (const float*)d_in[14]; const float* b2 = (const float*)d_in[15];
  const float* ln2w = (const float*)d_in[16]; const float* ln2b = (const float*)d_in[17];
  float* out = (float*)d_out;

  // Workspace: 4 x 8,388,608 floats = 128 MiB total. Overlays:
  //   attn_out -> qb (q dead after attention)
  //   x (LN1 out) -> d_out (final LN2 is row-wise in-place safe)
  //   h1 chunk [M,1024] -> kb (k dead after attention)
  //   ffn accumulator [M,D] -> vb (v dead after attention)
  const size_t NEED = (size_t)4 * 8388608 * sizeof(float);
  if (ws_size < NEED) return;  // clean failure instead of OOB fault

  float* ws  = (float*)d_ws;
  float* qb  = ws;               // [B,H,S,DK]
  float* kb  = ws + 8388608;     // [B,H,S,DK]
  float* vb  = ws + 16777216;    // [B,H,S,DK]
  float* ctx = ws + 25165824;    // [B,S,H*DK]
  float* attn_out = qb;
  float* xb  = out;
  float* h1c = kb;               // [M, 1024] FFN hidden chunk
  float* ffn = vb;               // [M, D] FFN output accumulator

  qkv_gemm<<<dim3(MM / 64, HH, 3), 256, 0, stream>>>(src, Wq, bq, Wk, bk, Wv, bv, qb, kb, vb);
  attention<<<dim3(SS / 8, HH, BB), 256, 0, stream>>>(qb, kb, vb, mask, ctx);
  gemm128<0, 0><<<dim3(DD / 128, MM / 128), 256, 0, stream>>>(ctx, Wo, bo, attn_out, MM, DD, DD, DD);
  residual_ln<<<MM, 256, 0, stream>>>(src, attn_out, ln1w, ln1b, xb);

  // FFN in 4 F-chunks of 1024: ffn (+)= ReLU(x @ W1[:,c] + b1[c]) @ W2[c,:]
  for (int fc = 0; fc < 4; ++fc) {
    gemm128<1, 0><<<dim3(1024 / 128, MM / 128), 256, 0, stream>>>(
        xb, W1 + fc * 1024, b1 + fc * 1024, h1c, MM, 1024, DD, FF);
    if (fc == 0)
      gemm128<0, 0><<<dim3(DD / 128, MM / 128), 256, 0, stream>>>(
          h1c, W2 + (size_t)fc * 1024 * DD, b2, ffn, MM, DD, 1024, DD);
    else
      gemm128<0, 1><<<dim3(DD / 128, MM / 128), 256, 0, stream>>>(
          h1c, W2 + (size_t)fc * 1024 * DD, b2, ffn, MM, DD, 1024, DD);
  }
  residual_ln<<<MM, 256, 0, stream>>>(xb, ffn, ln2w, ln2b, out);
}

// Round 3
// 2963.036 us; speedup vs baseline: 2.5963x; 2.5963x over previous
//
#include <hip/hip_runtime.h>

// Shapes (fixed by the reference)
#define BB 8
#define SS 1024
#define DD 1024
#define HH 16
#define DK 64
#define FF 4096
#define MM (BB*SS)   // 8192

typedef __attribute__((ext_vector_type(8))) short short8;
typedef __attribute__((ext_vector_type(4))) short short4v;
typedef __attribute__((ext_vector_type(4))) float floatx4;

__device__ inline short f2bf(float f) {
  union { float f; unsigned u; } v; v.f = f;
  unsigned r = (v.u + 0x7FFFu + ((v.u >> 16) & 1u)) >> 16;
  return (short)r;
}
__device__ inline float bf2f(unsigned short u) {
  union { unsigned u; float f; } v; v.u = ((unsigned)u) << 16;
  return v.f;
}

// ---------------------------------------------------------------------------
// QKV projection: fp32 accumulate, bf16 outputs.
// q,k layout [B,H,S,DK]; v written TRANSPOSED: vt [B,H,DK,S].
// grid (M/64, H, 3{q,k,v}), block 256.
// ---------------------------------------------------------------------------
__global__ __launch_bounds__(256) void qkv_gemm(
    const float* __restrict__ src,
    const float* __restrict__ Wq, const float* __restrict__ bq,
    const float* __restrict__ Wk, const float* __restrict__ bk,
    const float* __restrict__ Wv, const float* __restrict__ bv,
    unsigned short* __restrict__ qo, unsigned short* __restrict__ ko,
    unsigned short* __restrict__ vto) {
  const int m0 = blockIdx.x * 64;
  const int h  = blockIdx.y;
  const int z  = blockIdx.z;
  const float* W    = (z == 0 ? Wq : z == 1 ? Wk : Wv) + (size_t)h * DD * DK;
  const float* bias = (z == 0 ? bq : z == 1 ? bk : bv) + h * DK;

  __shared__ float As[16][64];   // [k][m] transposed
  __shared__ float Bs[16][64];   // [k][n]
  const int tid = threadIdx.x;
  const int tx = tid & 15, ty = tid >> 4;
  float acc[4][4] = {};

  for (int k0 = 0; k0 < DD; k0 += 16) {
    {
      int rowa = tid >> 2, c4 = (tid & 3) * 4;
      float4 av = *(const float4*)(src + (size_t)(m0 + rowa) * DD + k0 + c4);
      As[c4 + 0][rowa] = av.x; As[c4 + 1][rowa] = av.y;
      As[c4 + 2][rowa] = av.z; As[c4 + 3][rowa] = av.w;
    }
    {
      int rowb = tid >> 4, c4 = (tid & 15) * 4;
      *(float4*)(&Bs[rowb][c4]) = *(const float4*)(W + (size_t)(k0 + rowb) * DK + c4);
    }
    __syncthreads();
#pragma unroll
    for (int kk = 0; kk < 16; ++kk) {
      float4 a4 = *(float4*)(&As[kk][ty * 4]);
      float4 b4 = *(float4*)(&Bs[kk][tx * 4]);
      float a[4] = {a4.x, a4.y, a4.z, a4.w};
      float b[4] = {b4.x, b4.y, b4.z, b4.w};
#pragma unroll
      for (int i = 0; i < 4; ++i)
#pragma unroll
        for (int j = 0; j < 4; ++j) acc[i][j] += a[i] * b[j];
    }
    __syncthreads();
  }
  float4 bv4 = *(const float4*)(bias + tx * 4);
  float bb[4] = {bv4.x, bv4.y, bv4.z, bv4.w};
  const size_t hb = (size_t)((m0 >> 10) * HH + h);   // batch/head base (64|1024 so whole block same b)
#pragma unroll
  for (int i = 0; i < 4; ++i) {
    int m = m0 + ty * 4 + i;
    int s = m & 1023;
    if (z < 2) {
      unsigned short* out = (z == 0 ? qo : ko);
      short4v o;
      o[0] = f2bf(acc[i][0] + bb[0]); o[1] = f2bf(acc[i][1] + bb[1]);
      o[2] = f2bf(acc[i][2] + bb[2]); o[3] = f2bf(acc[i][3] + bb[3]);
      *(short4v*)(out + (hb * SS + s) * DK + tx * 4) = o;
    } else {
#pragma unroll
      for (int j = 0; j < 4; ++j)
        vto[(hb * DK + tx * 4 + j) * SS + s] = (unsigned short)f2bf(acc[i][j] + bb[j]);
    }
  }
}

// ---------------------------------------------------------------------------
// MFMA attention. Per block: 16 q-rows of one (b,h). 256 threads = 4 waves.
// Pass A: S = Q K^T via mfma_f32_16x16x32_bf16, scale+mask, bf16 logits to
//         LDS strip P[16][1032] (stride 1032 -> 2-way-only bank aliasing).
// Pass B: row softmax (one wave per 4 rows), unnormalized exp back to strip.
// Pass C: ctx^T = V^T @ P^T  (A-frag = contiguous vt rows, B-frag = contiguous
//         strip rows -> no cross-lane transpose needed), normalize, store.
// MFMA layouts (verified m89/m91/m120):
//   A: lane holds A[m=lane&15][k=quad*8+j];  B: lane holds B[k=quad*8+j][n=lane&15]
//   C/D: lane holds D[row=quad*4+reg][col=lane&15]
// ---------------------------------------------------------------------------
__global__ __launch_bounds__(256) void attention_mfma(
    const unsigned short* __restrict__ q, const unsigned short* __restrict__ k,
    const unsigned short* __restrict__ vt, const float* __restrict__ mask,
    float* __restrict__ ctx) {
  const int s0 = blockIdx.x * 16;
  const int h = blockIdx.y, b = blockIdx.z;
  const int tid = threadIdx.x;
  const int wave = tid >> 6, lane = tid & 63;
  const int lm = lane & 15, quad = lane >> 4;

  __shared__ unsigned short P[16 * 1032];  // 33 KB logits/P strip
  __shared__ float rs[16];                 // 1/rowsum

  const size_t base = (size_t)(b * HH + h) * SS * DK;

  // Q fragments: held in registers for the whole block
  const short8 qa0 = *(const short8*)(q + base + (size_t)(s0 + lm) * DK + quad * 8);
  const short8 qa1 = *(const short8*)(q + base + (size_t)(s0 + lm) * DK + quad * 8 + 32);

  // ---- pass A: logits ----
  for (int jt = 0; jt < 16; ++jt) {
    const int t0 = wave * 256 + jt * 16;
    short8 kb0 = *(const short8*)(k + base + (size_t)(t0 + lm) * DK + quad * 8);
    short8 kb1 = *(const short8*)(k + base + (size_t)(t0 + lm) * DK + quad * 8 + 32);
    floatx4 c = {0.f, 0.f, 0.f, 0.f};
    c = __builtin_amdgcn_mfma_f32_16x16x32_bf16(qa0, kb0, c, 0, 0, 0);
    c = __builtin_amdgcn_mfma_f32_16x16x32_bf16(qa1, kb1, c, 0, 0, 0);
#pragma unroll
    for (int r = 0; r < 4; ++r) {
      int row = quad * 4 + r;
      float sv = c[r] * 0.125f + mask[(size_t)(s0 + row) * SS + t0 + lm] * (-1e9f);
      P[row * 1032 + t0 + lm] = (unsigned short)f2bf(sv);
    }
  }
  __syncthreads();

  // ---- pass B: softmax per row (wave handles rows wave*4 .. wave*4+3) ----
#pragma unroll
  for (int ri = 0; ri < 4; ++ri) {
    const int row = wave * 4 + ri;
    unsigned short* prow = P + row * 1032 + lane * 16;
    short8 x0 = *(short8*)(prow);
    short8 x1 = *(short8*)(prow + 8);
    float f[16];
#pragma unroll
    for (int i = 0; i < 8; ++i) {
      f[i]     = bf2f((unsigned short)x0[i]);
      f[8 + i] = bf2f((unsigned short)x1[i]);
    }
    float mx = f[0];
#pragma unroll
    for (int i = 1; i < 16; ++i) mx = fmaxf(mx, f[i]);
#pragma unroll
    for (int o = 1; o < 64; o <<= 1) mx = fmaxf(mx, __shfl_xor(mx, o));
    float sm = 0.f;
#pragma unroll
    for (int i = 0; i < 16; ++i) { f[i] = __expf(f[i] - mx); sm += f[i]; }
#pragma unroll
    for (int o = 1; o < 64; o <<= 1) sm += __shfl_xor(sm, o);
#pragma unroll
    for (int i = 0; i < 8; ++i) { x0[i] = f2bf(f[i]); x1[i] = f2bf(f[8 + i]); }
    *(short8*)(prow) = x0;
    *(short8*)(prow + 8) = x1;
    if (lane == 0) rs[row] = 1.f / sm;
  }
  __syncthreads();

  // ---- pass C: ctx^T = V^T @ P^T; wave handles dv-tile [wave*16, wave*16+16) ----
  const int dv0 = wave * 16;
  const size_t vbase = (size_t)(b * HH + h) * DK * SS;
  floatx4 acc = {0.f, 0.f, 0.f, 0.f};
  for (int jt = 0; jt < 32; ++jt) {
    const int t0 = jt * 32;
    short8 va = *(const short8*)(vt + vbase + (size_t)(dv0 + lm) * SS + t0 + quad * 8);
    short8 pb = *(const short8*)(P + lm * 1032 + t0 + quad * 8);
    acc = __builtin_amdgcn_mfma_f32_16x16x32_bf16(va, pb, acc, 0, 0, 0);
  }
  const float sc = rs[lm];
#pragma unroll
  for (int r = 0; r < 4; ++r) {
    int dv = dv0 + quad * 4 + r;
    ctx[(size_t)(b * SS + s0 + lm) * DD + h * DK + dv] = acc[r] * sc;
  }
}

// ---------------------------------------------------------------------------
// Generic fp32 GEMM: C[M,N] = A[M,K] @ B[K,N] (+bias)(+ReLU)(+accumulate).
// B has row stride ldb (allows N-slices of a wider matrix).
// 128x128 tile, BK=16, 8x8 per thread, 256 threads.
// ---------------------------------------------------------------------------
template <int RELU, int ACC>
__global__ __launch_bounds__(256) void gemm128(
    const float* __restrict__ A, const float* __restrict__ Bm,
    const float* __restrict__ bias, float* __restrict__ C,
    int M, int N, int K, int ldb) {
  const int n0 = blockIdx.x * 128, m0 = blockIdx.y * 128;
  __shared__ float As[16][128];   // [k][m]
  __shared__ float Bs[16][128];   // [k][n]
  const int tid = threadIdx.x;
  const int tx = tid & 15, ty = tid >> 4;
  float acc[8][8] = {};

  const int arow = tid >> 1, ac = (tid & 1) * 8;
  const int brow = tid >> 4, bc = (tid & 15) * 8;

  for (int k0 = 0; k0 < K; k0 += 16) {
    float4 a0 = *(const float4*)(A + (size_t)(m0 + arow) * K + k0 + ac);
    float4 a1 = *(const float4*)(A + (size_t)(m0 + arow) * K + k0 + ac + 4);
    As[ac + 0][arow] = a0.x; As[ac + 1][arow] = a0.y;
    As[ac + 2][arow] = a0.z; As[ac + 3][arow] = a0.w;
    As[ac + 4][arow] = a1.x; As[ac + 5][arow] = a1.y;
    As[ac + 6][arow] = a1.z; As[ac + 7][arow] = a1.w;
    float4 b0 = *(const float4*)(Bm + (size_t)(k0 + brow) * ldb + n0 + bc);
    float4 b1 = *(const float4*)(Bm + (size_t)(k0 + brow) * ldb + n0 + bc + 4);
    *(float4*)(&Bs[brow][bc]) = b0;
    *(float4*)(&Bs[brow][bc + 4]) = b1;
    __syncthreads();
#pragma unroll
    for (int kk = 0; kk < 16; ++kk) {
      float a[8], b[8];
      *(float4*)(a)     = *(float4*)(&As[kk][ty * 8]);
      *(float4*)(a + 4) = *(float4*)(&As[kk][ty * 8 + 4]);
      *(float4*)(b)     = *(float4*)(&Bs[kk][tx * 8]);
      *(float4*)(b + 4) = *(float4*)(&Bs[kk][tx * 8 + 4]);
#pragma unroll
      for (int i = 0; i < 8; ++i)
#pragma unroll
        for (int j = 0; j < 8; ++j) acc[i][j] += a[i] * b[j];
    }
    __syncthreads();
  }

#pragma unroll
  for (int i = 0; i < 8; ++i) {
    int m = m0 + ty * 8 + i;
    float* crow = C + (size_t)m * N + n0 + tx * 8;
#pragma unroll
    for (int j4 = 0; j4 < 2; ++j4) {
      float4 o;
      if (ACC) {
        float4 c = *(float4*)(crow + j4 * 4);
        o.x = c.x + acc[i][j4 * 4 + 0];
        o.y = c.y + acc[i][j4 * 4 + 1];
        o.z = c.z + acc[i][j4 * 4 + 2];
        o.w = c.w + acc[i][j4 * 4 + 3];
      } else {
        const float* bp = bias + n0 + tx * 8 + j4 * 4;
        o.x = acc[i][j4 * 4 + 0] + bp[0];
        o.y = acc[i][j4 * 4 + 1] + bp[1];
        o.z = acc[i][j4 * 4 + 2] + bp[2];
        o.w = acc[i][j4 * 4 + 3] + bp[3];
        if (RELU) {
          o.x = fmaxf(o.x, 0.f); o.y = fmaxf(o.y, 0.f);
          o.z = fmaxf(o.z, 0.f); o.w = fmaxf(o.w, 0.f);
        }
      }
      *(float4*)(crow + j4 * 4) = o;
    }
  }
}

// ---------------------------------------------------------------------------
// Residual + LayerNorm: out = LN(a + r) * w + b. One block per row (D=1024).
// Safe for out == a (each thread reads its own 4 floats before writing them).
// ---------------------------------------------------------------------------
__global__ __launch_bounds__(256) void residual_ln(
    const float* __restrict__ a, const float* __restrict__ rr,
    const float* __restrict__ w, const float* __restrict__ bias,
    float* __restrict__ out) {
  const int row = blockIdx.x;
  const size_t off = (size_t)row * DD + threadIdx.x * 4;
  float4 va = *(const float4*)(a + off);
  float4 vr = *(const float4*)(rr + off);
  float4 x = {va.x + vr.x, va.y + vr.y, va.z + vr.z, va.w + vr.w};
  float s  = x.x + x.y + x.z + x.w;
  float ss = x.x * x.x + x.y * x.y + x.z * x.z + x.w * x.w;
#pragma unroll
  for (int o = 32; o > 0; o >>= 1) {
    s  += __shfl_down(s, o);
    ss += __shfl_down(ss, o);
  }
  __shared__ float2 sred[4];
  int wid = threadIdx.x >> 6;
  if ((threadIdx.x & 63) == 0) sred[wid] = make_float2(s, ss);
  __syncthreads();
  float st = 0.f, sst = 0.f;
#pragma unroll
  for (int i = 0; i < 4; ++i) { st += sred[i].x; sst += sred[i].y; }
  float mu  = st * (1.f / 1024.f);
  float var = sst * (1.f / 1024.f) - mu * mu;
  float rsq = rsqrtf(var + 1e-5f);
  float4 vw = *(const float4*)(w + threadIdx.x * 4);
  float4 vb = *(const float4*)(bias + threadIdx.x * 4);
  float4 o;
  o.x = (x.x - mu) * rsq * vw.x + vb.x;
  o.y = (x.y - mu) * rsq * vw.y + vb.y;
  o.z = (x.z - mu) * rsq * vw.z + vb.z;
  o.w = (x.w - mu) * rsq * vw.w + vb.w;
  *(float4*)(out + off) = o;
}

// ---------------------------------------------------------------------------
extern "C" void kernel_launch(void* const* d_in, const int* in_sizes, int n_in,
                              void* d_out, int out_size, void* d_ws, size_t ws_size,
                              hipStream_t stream) {
  const float* src  = (const float*)d_in[0];
  const float* mask = (const float*)d_in[1];
  const float* Wq = (const float*)d_in[2];  const float* bq = (const float*)d_in[3];
  const float* Wk = (const float*)d_in[4];  const float* bk = (const float*)d_in[5];
  const float* Wv = (const float*)d_in[6];  const float* bv = (const float*)d_in[7];
  const float* Wo = (const float*)d_in[8];  const float* bo = (const float*)d_in[9];
  const float* ln1w = (const float*)d_in[10]; const float* ln1b = (const float*)d_in[11];
  const float* W1 = (const float*)d_in[12]; const float* b1 = (const float*)d_in[13];
  const float* W2 = (const float*)d_in[14]; const float* b2 = (const float*)d_in[15];
  const float* ln2w = (const float*)d_in[16]; const float* ln2b = (const float*)d_in[17];
  float* out = (float*)d_out;

  // Workspace (96 MiB):
  //  [ 0,32M)  ctx (fp32)
  //  [32,64M)  attn_out (fp32, phase 3-4) / h1c (fp32, phase 5) ; also qb+kb (bf16,
  //            phases 1-2, dead before attn_out is written)
  //  [64,96M)  ffn accumulator (fp32, phase 5) ; also kb tail + vtb (bf16, dead
  //            before ffn is written)
  const size_t NEED = (size_t)96 * 1024 * 1024;
  if (ws_size < NEED) return;  // clean failure instead of OOB fault

  float* ws = (float*)d_ws;
  float* ctx      = ws;                    // [B,S,H*DK] fp32
  float* attn_out = ws + 8388608;
  float* h1c      = attn_out;              // [M,1024] FFN hidden chunk
  float* ffn      = ws + 16777216;         // [M,D] FFN accumulator
  unsigned short* qb  = (unsigned short*)(ws + 8388608);  // [B,H,S,DK] bf16
  unsigned short* kb  = qb + 8388608;                     // [B,H,S,DK] bf16
  unsigned short* vtb = kb + 8388608;                     // [B,H,DK,S] bf16
  float* xb = out;

  qkv_gemm<<<dim3(MM / 64, HH, 3), 256, 0, stream>>>(src, Wq, bq, Wk, bk, Wv, bv, qb, kb, vtb);
  attention_mfma<<<dim3(SS / 16, HH, BB), 256, 0, stream>>>(qb, kb, vtb, mask, ctx);
  gemm128<0, 0><<<dim3(DD / 128, MM / 128), 256, 0, stream>>>(ctx, Wo, bo, attn_out, MM, DD, DD, DD);
  residual_ln<<<MM, 256, 0, stream>>>(src, attn_out, ln1w, ln1b, xb);

  // FFN in 4 F-chunks of 1024: ffn (+)= ReLU(x @ W1[:,c] + b1[c]) @ W2[c,:]
  for (int fc = 0; fc < 4; ++fc) {
    gemm128<1, 0><<<dim3(1024 / 128, MM / 128), 256, 0, stream>>>(
        xb, W1 + fc * 1024, b1 + fc * 1024, h1c, MM, 1024, DD, FF);
    if (fc == 0)
      gemm128<0, 0><<<dim3(DD / 128, MM / 128), 256, 0, stream>>>(
          h1c, W2 + (size_t)fc * 1024 * DD, b2, ffn, MM, DD, 1024, DD);
    else
      gemm128<0, 1><<<dim3(DD / 128, MM / 128), 256, 0, stream>>>(
          h1c, W2 + (size_t)fc * 1024 * DD, b2, ffn, MM, DD, 1024, DD);
  }
  residual_ln<<<MM, 256, 0, stream>>>(xb, ffn, ln2w, ln2b, out);
}

// Round 4
// 744.978 us; speedup vs baseline: 10.3265x; 3.9773x over previous
//
#include <hip/hip_runtime.h>

// Shapes (fixed by the reference)
#define BB 8
#define SS 1024
#define DD 1024
#define HH 16
#define DK 64
#define FF 4096
#define MM (BB*SS)   // 8192

typedef __attribute__((ext_vector_type(8))) short short8;
typedef __attribute__((ext_vector_type(4))) short short4v;
typedef __attribute__((ext_vector_type(4))) float floatx4;

__device__ inline short f2bf(float f) {
  union { float f; unsigned u; } v; v.f = f;
  unsigned r = (v.u + 0x7FFFu + ((v.u >> 16) & 1u)) >> 16;
  return (short)r;
}
__device__ inline float bf2f(unsigned short u) {
  union { unsigned u; float f; } v; v.u = ((unsigned)u) << 16;
  return v.f;
}

// async global->LDS, 16B per lane; lds dst must be wave-uniform base (+lane*16)
__device__ inline void gload_lds16(const void* g, void* l) {
  __builtin_amdgcn_global_load_lds(
      (const __attribute__((address_space(1))) void*)g,
      (__attribute__((address_space(3))) void*)l, 16, 0, 0);
}

// ---------------------------------------------------------------------------
// fp32 -> bf16 elementwise (8 per thread)
// ---------------------------------------------------------------------------
__global__ __launch_bounds__(256) void cvt_bf16(
    const float* __restrict__ in, unsigned short* __restrict__ out, int n) {
  int i8 = (blockIdx.x * 256 + threadIdx.x) * 8;
  if (i8 >= n) return;
  float4 a = *(const float4*)(in + i8);
  float4 b = *(const float4*)(in + i8 + 4);
  short8 o;
  o[0] = f2bf(a.x); o[1] = f2bf(a.y); o[2] = f2bf(a.z); o[3] = f2bf(a.w);
  o[4] = f2bf(b.x); o[5] = f2bf(b.y); o[6] = f2bf(b.z); o[7] = f2bf(b.w);
  *(short8*)(out + i8) = o;
}

// ---------------------------------------------------------------------------
// Build WqkvT [3072,1024] bf16: WqkvT[z*1024+h*64+dk][d] = Wz[h][d][dk].
// grid (D/64, H, 3), block 256. Transposes one [64d x 64dk] tile.
// ---------------------------------------------------------------------------
__global__ __launch_bounds__(256) void prep_wqkv(
    const float* __restrict__ Wq, const float* __restrict__ Wk,
    const float* __restrict__ Wv, unsigned short* __restrict__ wt) {
  const int d0 = blockIdx.x * 64, h = blockIdx.y, z = blockIdx.z;
  const float* W = (z == 0 ? Wq : z == 1 ? Wk : Wv) + (size_t)h * DD * DK;
  __shared__ float ld[64][68];
  const int tid = threadIdx.x;
  {
    int r = tid >> 2, c16 = (tid & 3) * 16;
#pragma unroll
    for (int i = 0; i < 4; ++i)
      *(float4*)(&ld[r][c16 + i * 4]) = *(const float4*)(W + (size_t)(d0 + r) * DK + c16 + i * 4);
  }
  __syncthreads();
  int dv = tid >> 2, d16 = (tid & 3) * 16;
  short8 o0, o1;
#pragma unroll
  for (int i = 0; i < 8; ++i) {
    o0[i] = f2bf(ld[d16 + i][dv]);
    o1[i] = f2bf(ld[d16 + 8 + i][dv]);
  }
  unsigned short* dst = wt + (size_t)(z * 1024 + h * 64 + dv) * DD + d0 + d16;
  *(short8*)(dst) = o0;
  *(short8*)(dst + 8) = o1;
}

__global__ __launch_bounds__(256) void prep_bias(
    const float* __restrict__ bq, const float* __restrict__ bk,
    const float* __restrict__ bv, float* __restrict__ bqkv) {
  int n = blockIdx.x * 256 + threadIdx.x;   // 0..3071
  int z = n >> 10;
  const float* s = (z == 0 ? bq : z == 1 ? bk : bv);
  bqkv[n] = s[n & 1023];
}

// ---------------------------------------------------------------------------
// Generic transpose fp32 [R][C] -> bf16 [C][R]. grid (R/64, C/64), block 256.
// ---------------------------------------------------------------------------
__global__ __launch_bounds__(256) void transpose_w(
    const float* __restrict__ src, unsigned short* __restrict__ dst,
    int R, int C) {
  const int r0 = blockIdx.x * 64, c0 = blockIdx.y * 64;
  __shared__ float ld[64][68];
  const int tid = threadIdx.x;
  {
    int r = tid >> 2, c16 = (tid & 3) * 16;
#pragma unroll
    for (int i = 0; i < 4; ++i)
      *(float4*)(&ld[r][c16 + i * 4]) =
          *(const float4*)(src + (size_t)(r0 + r) * C + c0 + c16 + i * 4);
  }
  __syncthreads();
  int c = tid >> 2, r16 = (tid & 3) * 16;
  short8 o0, o1;
#pragma unroll
  for (int i = 0; i < 8; ++i) {
    o0[i] = f2bf(ld[r16 + i][c]);
    o1[i] = f2bf(ld[r16 + 8 + i][c]);
  }
  unsigned short* d = dst + (size_t)(c0 + c) * R + r0 + r16;
  *(short8*)(d) = o0;
  *(short8*)(d + 8) = o1;
}

// ---------------------------------------------------------------------------
// V transpose from qkv buffer: vt[b,h,dv,t] = qkv[(b*S+t)*3072 + 2048 + h*64 + dv]
// grid (S/64, H, B), block 256.
// ---------------------------------------------------------------------------
__global__ __launch_bounds__(256) void transpose_v(
    const unsigned short* __restrict__ qkv, unsigned short* __restrict__ vt) {
  const int t0 = blockIdx.x * 64, h = blockIdx.y, b = blockIdx.z;
  __shared__ unsigned short ld[64][72];
  const int tid = threadIdx.x;
  {
    int r = tid >> 2, c16 = (tid & 3) * 16;
    const unsigned short* s = qkv + (size_t)(b * SS + t0 + r) * 3072 + 2048 + h * 64 + c16;
    *(short8*)(&ld[r][c16]) = *(const short8*)(s);
    *(short8*)(&ld[r][c16 + 8]) = *(const short8*)(s + 8);
  }
  __syncthreads();
  int dv = tid >> 2, t16 = (tid & 3) * 16;
  short8 o0, o1;
#pragma unroll
  for (int i = 0; i < 8; ++i) {
    o0[i] = (short)ld[t16 + i][dv];
    o1[i] = (short)ld[t16 + 8 + i][dv];
  }
  unsigned short* d = vt + ((size_t)(b * HH + h) * DK + dv) * SS + t0 + t16;
  *(short8*)(d) = o0;
  *(short8*)(d + 8) = o1;
}

// ---------------------------------------------------------------------------
// bf16 MFMA GEMM (m97 structure): C[M,N] = A[M,K] @ B[K,N] + bias (+ReLU),
// A row-major bf16, Bt = B^T [N,K] row-major bf16, C bf16, bias fp32.
// 128x128 tile, BK=32, 256 thr = 4 waves (2x2 of 64x64), global_load_lds.
// ---------------------------------------------------------------------------
template <int RELU>
__global__ __launch_bounds__(256) void gemm_bf16(
    const unsigned short* __restrict__ A, const unsigned short* __restrict__ Bt,
    const float* __restrict__ bias, unsigned short* __restrict__ C,
    int M, int N, int K) {
  const int n0 = blockIdx.x * 128, m0 = blockIdx.y * 128;
  __shared__ __align__(16) unsigned short As[128 * 32];
  __shared__ __align__(16) unsigned short Bs[128 * 32];
  const int tid = threadIdx.x;
  const int wave = tid >> 6, lane = tid & 63;
  const int lm = lane & 15, quad = lane >> 4;
  const int wr = wave >> 1, wc = wave & 1;
  const int srow = lane >> 2;        // 0..15 (staging row within 16-row chunk)
  const int scol = (lane & 3) * 8;   // bf16 offset within row (16B granules)

  floatx4 acc[4][4] = {};

  for (int k0 = 0; k0 < K; k0 += 32) {
#pragma unroll
    for (int j = 0; j < 2; ++j) {
      int rr = wave * 32 + j * 16;
      gload_lds16(A + (size_t)(m0 + rr + srow) * K + k0 + scol, &As[rr * 32]);
      gload_lds16(Bt + (size_t)(n0 + rr + srow) * K + k0 + scol, &Bs[rr * 32]);
    }
    __syncthreads();
    short8 af[4], bf[4];
#pragma unroll
    for (int i = 0; i < 4; ++i)
      af[i] = *(const short8*)&As[(wr * 64 + i * 16 + lm) * 32 + quad * 8];
#pragma unroll
    for (int j = 0; j < 4; ++j)
      bf[j] = *(const short8*)&Bs[(wc * 64 + j * 16 + lm) * 32 + quad * 8];
#pragma unroll
    for (int i = 0; i < 4; ++i)
#pragma unroll
      for (int j = 0; j < 4; ++j)
        acc[i][j] = __builtin_amdgcn_mfma_f32_16x16x32_bf16(af[i], bf[j], acc[i][j], 0, 0, 0);
    __syncthreads();
  }

#pragma unroll
  for (int i = 0; i < 4; ++i) {
#pragma unroll
    for (int j = 0; j < 4; ++j) {
      int col = n0 + wc * 64 + j * 16 + lm;
      float bv = bias[col];
#pragma unroll
      for (int r = 0; r < 4; ++r) {
        int row = m0 + wr * 64 + i * 16 + quad * 4 + r;
        float v = acc[i][j][r] + bv;
        if (RELU) v = fmaxf(v, 0.f);
        C[(size_t)row * N + col] = (unsigned short)f2bf(v);
      }
    }
  }
}

// ---------------------------------------------------------------------------
// MFMA attention (round-3 verified structure). q,k read from fused qkv buffer
// [M,3072] (q at col h*64, k at col 1024+h*64); vt [B,H,DK,S]; ctx out bf16.
// ---------------------------------------------------------------------------
__global__ __launch_bounds__(256) void attention_mfma(
    const unsigned short* __restrict__ qkv, const unsigned short* __restrict__ vt,
    const float* __restrict__ mask, unsigned short* __restrict__ ctx) {
  const int s0 = blockIdx.x * 16;
  const int h = blockIdx.y, b = blockIdx.z;
  const int tid = threadIdx.x;
  const int wave = tid >> 6, lane = tid & 63;
  const int lm = lane & 15, quad = lane >> 4;

  __shared__ unsigned short P[16 * 1032];  // 33 KB logits/P strip
  __shared__ float rs[16];                 // 1/rowsum

  const unsigned short* qp = qkv + (size_t)(b * SS + s0 + lm) * 3072 + h * 64;
  const short8 qa0 = *(const short8*)(qp + quad * 8);
  const short8 qa1 = *(const short8*)(qp + quad * 8 + 32);

  // ---- pass A: logits ----
  for (int jt = 0; jt < 16; ++jt) {
    const int t0 = wave * 256 + jt * 16;
    const unsigned short* kp = qkv + (size_t)(b * SS + t0 + lm) * 3072 + 1024 + h * 64;
    short8 kb0 = *(const short8*)(kp + quad * 8);
    short8 kb1 = *(const short8*)(kp + quad * 8 + 32);
    floatx4 c = {0.f, 0.f, 0.f, 0.f};
    c = __builtin_amdgcn_mfma_f32_16x16x32_bf16(qa0, kb0, c, 0, 0, 0);
    c = __builtin_amdgcn_mfma_f32_16x16x32_bf16(qa1, kb1, c, 0, 0, 0);
#pragma unroll
    for (int r = 0; r < 4; ++r) {
      int row = quad * 4 + r;
      float sv = c[r] * 0.125f + mask[(size_t)(s0 + row) * SS + t0 + lm] * (-1e9f);
      P[row * 1032 + t0 + lm] = (unsigned short)f2bf(sv);
    }
  }
  __syncthreads();

  // ---- pass B: softmax per row ----
#pragma unroll
  for (int ri = 0; ri < 4; ++ri) {
    const int row = wave * 4 + ri;
    unsigned short* prow = P + row * 1032 + lane * 16;
    short8 x0 = *(short8*)(prow);
    short8 x1 = *(short8*)(prow + 8);
    float f[16];
#pragma unroll
    for (int i = 0; i < 8; ++i) {
      f[i]     = bf2f((unsigned short)x0[i]);
      f[8 + i] = bf2f((unsigned short)x1[i]);
    }
    float mx = f[0];
#pragma unroll
    for (int i = 1; i < 16; ++i) mx = fmaxf(mx, f[i]);
#pragma unroll
    for (int o = 1; o < 64; o <<= 1) mx = fmaxf(mx, __shfl_xor(mx, o));
    float sm = 0.f;
#pragma unroll
    for (int i = 0; i < 16; ++i) { f[i] = __expf(f[i] - mx); sm += f[i]; }
#pragma unroll
    for (int o = 1; o < 64; o <<= 1) sm += __shfl_xor(sm, o);
#pragma unroll
    for (int i = 0; i < 8; ++i) { x0[i] = f2bf(f[i]); x1[i] = f2bf(f[8 + i]); }
    *(short8*)(prow) = x0;
    *(short8*)(prow + 8) = x1;
    if (lane == 0) rs[row] = 1.f / sm;
  }
  __syncthreads();

  // ---- pass C: ctx^T = V^T @ P^T ----
  const int dv0 = wave * 16;
  const size_t vbase = (size_t)(b * HH + h) * DK * SS;
  floatx4 acc = {0.f, 0.f, 0.f, 0.f};
  for (int jt = 0; jt < 32; ++jt) {
    const int t0 = jt * 32;
    short8 va = *(const short8*)(vt + vbase + (size_t)(dv0 + lm) * SS + t0 + quad * 8);
    short8 pb = *(const short8*)(P + lm * 1032 + t0 + quad * 8);
    acc = __builtin_amdgcn_mfma_f32_16x16x32_bf16(va, pb, acc, 0, 0, 0);
  }
  const float sc = rs[lm];
#pragma unroll
  for (int r = 0; r < 4; ++r) {
    int dv = dv0 + quad * 4 + r;
    ctx[(size_t)(b * SS + s0 + lm) * DD + h * DK + dv] = (unsigned short)f2bf(acc[r] * sc);
  }
}

// ---------------------------------------------------------------------------
// Residual + LayerNorm: out = LN(a + r) * w + b. One block per row (D=1024).
// a: fp32 or bf16; r: bf16; out: fp32 or bf16.
// ---------------------------------------------------------------------------
template <int A_BF16, int OUT_BF16>
__global__ __launch_bounds__(256) void residual_ln(
    const void* __restrict__ a_, const unsigned short* __restrict__ rr,
    const float* __restrict__ w, const float* __restrict__ bias,
    void* __restrict__ out_) {
  const int row = blockIdx.x;
  const int t = threadIdx.x;
  float x[4];
  if (A_BF16) {
    short4v va = *(const short4v*)((const unsigned short*)a_ + (size_t)row * DD + t * 4);
#pragma unroll
    for (int i = 0; i < 4; ++i) x[i] = bf2f((unsigned short)va[i]);
  } else {
    float4 va = *(const float4*)((const float*)a_ + (size_t)row * DD + t * 4);
    x[0] = va.x; x[1] = va.y; x[2] = va.z; x[3] = va.w;
  }
  {
    short4v vr = *(const short4v*)(rr + (size_t)row * DD + t * 4);
#pragma unroll
    for (int i = 0; i < 4; ++i) x[i] += bf2f((unsigned short)vr[i]);
  }
  float s = 0.f, ss = 0.f;
#pragma unroll
  for (int i = 0; i < 4; ++i) { s += x[i]; ss += x[i] * x[i]; }
#pragma unroll
  for (int o = 32; o > 0; o >>= 1) {
    s  += __shfl_down(s, o);
    ss += __shfl_down(ss, o);
  }
  __shared__ float2 sred[4];
  int wid = t >> 6;
  if ((t & 63) == 0) sred[wid] = make_float2(s, ss);
  __syncthreads();
  float st = 0.f, sst = 0.f;
#pragma unroll
  for (int i = 0; i < 4; ++i) { st += sred[i].x; sst += sred[i].y; }
  float mu  = st * (1.f / 1024.f);
  float var = sst * (1.f / 1024.f) - mu * mu;
  float rsq = rsqrtf(var + 1e-5f);
  float4 vw = *(const float4*)(w + t * 4);
  float4 vb = *(const float4*)(bias + t * 4);
  float o[4];
  o[0] = (x[0] - mu) * rsq * vw.x + vb.x;
  o[1] = (x[1] - mu) * rsq * vw.y + vb.y;
  o[2] = (x[2] - mu) * rsq * vw.z + vb.z;
  o[3] = (x[3] - mu) * rsq * vw.w + vb.w;
  if (OUT_BF16) {
    short4v ov;
#pragma unroll
    for (int i = 0; i < 4; ++i) ov[i] = f2bf(o[i]);
    *(short4v*)((unsigned short*)out_ + (size_t)row * DD + t * 4) = ov;
  } else {
    float4 ov = {o[0], o[1], o[2], o[3]};
    *(float4*)((float*)out_ + (size_t)row * DD + t * 4) = ov;
  }
}

// ---------------------------------------------------------------------------
extern "C" void kernel_launch(void* const* d_in, const int* in_sizes, int n_in,
                              void* d_out, int out_size, void* d_ws, size_t ws_size,
                              hipStream_t stream) {
  const float* src  = (const float*)d_in[0];
  const float* mask = (const float*)d_in[1];
  const float* Wq = (const float*)d_in[2];  const float* bq = (const float*)d_in[3];
  const float* Wk = (const float*)d_in[4];  const float* bk = (const float*)d_in[5];
  const float* Wv = (const float*)d_in[6];  const float* bv = (const float*)d_in[7];
  const float* Wo = (const float*)d_in[8];  const float* bo = (const float*)d_in[9];
  const float* ln1w = (const float*)d_in[10]; const float* ln1b = (const float*)d_in[11];
  const float* W1 = (const float*)d_in[12]; const float* b1 = (const float*)d_in[13];
  const float* W2 = (const float*)d_in[14]; const float* b2 = (const float*)d_in[15];
  const float* ln2w = (const float*)d_in[16]; const float* ln2b = (const float*)d_in[17];
  float* out = (float*)d_out;

  // Workspace layout (byte offsets), total 125,841,408 B (~120 MiB):
  //  [  0, 48M)  qkv bf16 [M,3072]          -> h1 bf16 [M,4096] (after LN1)
  //  [ 48, 64M)  vt bf16 [B,H,DK,S]         -> attn_out bf16 (after attention)
  //  [ 64, 80M)  ctx bf16 [M,1024]          -> xb bf16 (after Wo gemm)
  //  [ 80, 96M)  srcb bf16 [M,1024]         -> ffn bf16 (after QKV gemm)
  //  [ 96,120M)  weights: wqkvT, woT, w1T, w2T, bqkv
  const size_t NEED = 125841408;
  if (ws_size < NEED) return;

  char* ws = (char*)d_ws;
  unsigned short* qkv   = (unsigned short*)(ws);
  unsigned short* vtb   = (unsigned short*)(ws + 50331648);
  unsigned short* ctxb  = (unsigned short*)(ws + 67108864);
  unsigned short* srcb  = (unsigned short*)(ws + 83886080);
  unsigned short* wqkvT = (unsigned short*)(ws + 100663296);  // [3072,1024]
  unsigned short* woT   = (unsigned short*)(ws + 106954752);  // [1024,1024]
  unsigned short* w1T   = (unsigned short*)(ws + 109051904);  // [4096,1024]
  unsigned short* w2T   = (unsigned short*)(ws + 117440512);  // [1024,4096]
  float*          bqkv  = (float*)(ws + 125829120);           // [3072]
  unsigned short* h1       = qkv;   // [M,4096] spans qkv+vtb
  unsigned short* attn_out = vtb;
  unsigned short* xb       = ctxb;
  unsigned short* ffn      = srcb;

  // ---- prep (bf16 casts + weight transposes) ----
  cvt_bf16<<<MM * DD / (256 * 8), 256, 0, stream>>>(src, srcb, MM * DD);
  prep_wqkv<<<dim3(DD / 64, HH, 3), 256, 0, stream>>>(Wq, Wk, Wv, wqkvT);
  prep_bias<<<12, 256, 0, stream>>>(bq, bk, bv, bqkv);
  transpose_w<<<dim3(16, 16), 256, 0, stream>>>(Wo, woT, 1024, 1024);
  transpose_w<<<dim3(16, 64), 256, 0, stream>>>(W1, w1T, 1024, 4096);
  transpose_w<<<dim3(64, 16), 256, 0, stream>>>(W2, w2T, 4096, 1024);

  // ---- main pipeline ----
  gemm_bf16<0><<<dim3(3072 / 128, MM / 128), 256, 0, stream>>>(srcb, wqkvT, bqkv, qkv, MM, 3072, DD);
  transpose_v<<<dim3(SS / 64, HH, BB), 256, 0, stream>>>(qkv, vtb);
  attention_mfma<<<dim3(SS / 16, HH, BB), 256, 0, stream>>>(qkv, vtb, mask, ctxb);
  gemm_bf16<0><<<dim3(DD / 128, MM / 128), 256, 0, stream>>>(ctxb, woT, bo, attn_out, MM, DD, DD);
  residual_ln<0, 1><<<MM, 256, 0, stream>>>(src, attn_out, ln1w, ln1b, xb);
  gemm_bf16<1><<<dim3(FF / 128, MM / 128), 256, 0, stream>>>(xb, w1T, b1, h1, MM, FF, DD);
  gemm_bf16<0><<<dim3(DD / 128, MM / 128), 256, 0, stream>>>(h1, w2T, b2, ffn, MM, DD, FF);
  residual_ln<1, 0><<<MM, 256, 0, stream>>>(xb, ffn, ln2w, ln2b, out);
}